// Round 12
// baseline (96.533 us; speedup 1.0000x reference)
//
#include <hip/hip_runtime.h>

#define M_DIM 64
#define K_DIM 8192
#define N_DIM 10240
#define KSPLIT 8
#define KBLK (K_DIM / KSPLIT)    // 1024 k per block
#define KSTEP 128                 // k per chunk (ints)
#define NCHUNK (KBLK / KSTEP)     // 8
#define NTILE 64                  // n cols per block (4 waves x 16)

typedef __attribute__((ext_vector_type(8))) short short8;
typedef __attribute__((ext_vector_type(4))) float f32x4;
typedef __attribute__((ext_vector_type(4))) int i32x4;

// exact for integer-valued floats |v| <= 127
static __device__ __forceinline__ ushort f2bf_trunc(float f) {
    return (ushort)(__float_as_uint(f) >> 16);
}

// ---------------- Kernel 1: per-token dynamic int8 quantization ----------------
// (verbatim — verified rounds 5/11)
__global__ __launch_bounds__(256) void quant_kernel(
    const float* __restrict__ x,
    ushort* __restrict__ xq,
    float* __restrict__ xscale) {
    const int m = blockIdx.x;
    const int tid = threadIdx.x;
    const float4* xrow = (const float4*)(x + m * K_DIM);
    float4 c[8];
    float mx = 0.f;
#pragma unroll
    for (int i = 0; i < 8; ++i) {
        c[i] = xrow[i * 256 + tid];
        mx = fmaxf(mx, fmaxf(fmaxf(fabsf(c[i].x), fabsf(c[i].y)),
                             fmaxf(fabsf(c[i].z), fabsf(c[i].w))));
    }
#pragma unroll
    for (int off = 32; off; off >>= 1) mx = fmaxf(mx, __shfl_xor(mx, off));
    __shared__ float wmax[4];
    if ((tid & 63) == 0) wmax[tid >> 6] = mx;
    __syncthreads();
    mx = fmaxf(fmaxf(wmax[0], wmax[1]), fmaxf(wmax[2], wmax[3]));
    const float s = mx / 127.0f;
    if (tid == 0) xscale[m] = s;

    ushort4* qrow = (ushort4*)(xq + m * K_DIM);
#pragma unroll
    for (int i = 0; i < 8; ++i) {
        float q0 = fminf(fmaxf(rintf(c[i].x / s), -127.f), 127.f);
        float q1 = fminf(fmaxf(rintf(c[i].y / s), -127.f), 127.f);
        float q2 = fminf(fmaxf(rintf(c[i].z / s), -127.f), 127.f);
        float q3 = fminf(fmaxf(rintf(c[i].w / s), -127.f), 127.f);
        ushort4 o;
        o.x = f2bf_trunc(q0);
        o.y = f2bf_trunc(q1);
        o.z = f2bf_trunc(q2);
        o.w = f2bf_trunc(q3);
        qrow[i * 256 + tid] = o;
    }
}

// ---------------- Kernel 2: round-11 verified core, atomic epilogue ------------
// grid (160, 8), 4 waves, 64 KB LDS -> 2 blocks/CU. ONLY change vs round 11:
// the epilogue. Partials + LDS-coalesce replaced by exact-integer f32
// atomicAdd into a pre-zeroed accumulator (order-independent => deterministic).
__global__ __launch_bounds__(256, 2) void gemm_kernel(
    const ushort* __restrict__ xq,   // bf16 bits [64, 8192]
    const int* __restrict__ W,       // int32 [10240, 8192], |v| <= 127
    float* __restrict__ accum) {     // f32 [64, 10240], pre-zeroed
    const int tid = threadIdx.x;
    const int w = tid >> 6;
    const int lane = tid & 63;
    const int r16 = lane & 15;
    const int kgrp = lane >> 4;
    const int n0 = blockIdx.x * NTILE;
    const int k0 = blockIdx.y * KBLK;

    __shared__ __align__(16) ushort Abuf[2][NTILE * KSTEP];  // 2 x 16 KB
    __shared__ __align__(16) ushort Bbuf[2][NTILE * KSTEP];  // 2 x 16 KB

    i32x4 aB[8];    // W staging: 8 instrs x (2 rows x 512B) contiguous
    short8 aA[4];   // A staging: 4 instrs x (4 rows x 256B) contiguous

#define ISSUE_B(c)                                                             \
    {                                                                          \
        const int* base = W + k0 + (c) * KSTEP + (lane & 31) * 4;              \
        _Pragma("unroll") for (int i = 0; i < 8; ++i) {                        \
            const int row = n0 + w * 16 + i * 2 + (lane >> 5);                 \
            aB[i] = *(const i32x4*)(base + (size_t)row * K_DIM);               \
        }                                                                      \
    }
#define ISSUE_A(c)                                                             \
    {                                                                          \
        const ushort* base = xq + k0 + (c) * KSTEP + (lane & 15) * 8;          \
        _Pragma("unroll") for (int i = 0; i < 4; ++i) {                        \
            const int row = w * 16 + i * 4 + (lane >> 4);                      \
            aA[i] = *(const short8*)(base + row * K_DIM);                      \
        }                                                                      \
    }
#define WRITE_A(bufi)                                                          \
    {                                                                          \
        _Pragma("unroll") for (int i = 0; i < 4; ++i) {                        \
            const int row = w * 16 + i * 4 + (lane >> 4);                      \
            const int off = ((lane & 15) * 16) ^ ((row & 7) << 4);             \
            *(short8*)((char*)&Abuf[bufi][row * KSTEP] + off) = aA[i];         \
        }                                                                      \
    }
#define WRITE_B(bufi)                                                          \
    {                                                                          \
        _Pragma("unroll") for (int i = 0; i < 8; ++i) {                        \
            const int row = w * 16 + i * 2 + (lane >> 5);                      \
            ushort4 h;                                                         \
            h.x = f2bf_trunc((float)aB[i][0]);                                 \
            h.y = f2bf_trunc((float)aB[i][1]);                                 \
            h.z = f2bf_trunc((float)aB[i][2]);                                 \
            h.w = f2bf_trunc((float)aB[i][3]);                                 \
            const int off = ((lane & 31) * 8) ^ ((row & 7) << 4);              \
            *(ushort4*)((char*)&Bbuf[bufi][row * KSTEP] + off) = h;            \
        }                                                                      \
    }
#define COMPUTE(bufi)                                                          \
    {                                                                          \
        _Pragma("unroll") for (int ks = 0; ks < 4; ++ks) {                     \
            const int swz = (ks * 64 + kgrp * 16) ^ ((r16 & 7) << 4);          \
            short8 bfrag = *(const short8*)(                                   \
                (char*)&Bbuf[bufi][(w * 16 + r16) * KSTEP] + swz);             \
            _Pragma("unroll") for (int mt = 0; mt < 4; ++mt) {                 \
                short8 afrag = *(const short8*)(                               \
                    (char*)&Abuf[bufi][(mt * 16 + r16) * KSTEP] + swz);        \
                acc[mt] = __builtin_amdgcn_mfma_f32_16x16x32_bf16(             \
                    afrag, bfrag, acc[mt], 0, 0, 0);                           \
            }                                                                  \
        }                                                                      \
    }

    f32x4 acc[4];
#pragma unroll
    for (int i = 0; i < 4; ++i) acc[i] = (f32x4){0.f, 0.f, 0.f, 0.f};

    // prologue: chunk 0 staged; chunk 1 in flight (verified pattern)
    ISSUE_B(0)
    ISSUE_A(0)
    WRITE_A(0)
    WRITE_B(0)
    __syncthreads();
    ISSUE_B(1)
    ISSUE_A(1)

#pragma unroll
    for (int c = 0; c < NCHUNK; ++c) {
        COMPUTE(c & 1);
        if (c < NCHUNK - 1) {
            __syncthreads();  // all waves done reading buf (c+1)&1's old data
            WRITE_A((c + 1) & 1)
            WRITE_B((c + 1) & 1)
            if (c + 2 < NCHUNK) {
                ISSUE_B(c + 2)
                ISSUE_A(c + 2)
            }
            __syncthreads();  // new chunk visible
        }
    }

    // epilogue: exact-integer f32 atomic accumulation (order-independent)
#pragma unroll
    for (int mt = 0; mt < 4; ++mt)
#pragma unroll
        for (int j = 0; j < 4; ++j) {
            const int m = mt * 16 + kgrp * 4 + j;
            atomicAdd(&accum[m * N_DIM + n0 + w * 16 + r16], acc[mt][j]);
        }
#undef ISSUE_B
#undef ISSUE_A
#undef WRITE_A
#undef WRITE_B
#undef COMPUTE
}

// ---------------- Kernel 3: dequant + bias ------------------------------------
__global__ __launch_bounds__(256) void finalize_kernel(
    const float* __restrict__ accum,
    const float* __restrict__ xscale,
    const float* __restrict__ wscale,
    const float* __restrict__ bias,
    float* __restrict__ out) {
    const int idx = blockIdx.x * 256 + threadIdx.x;  // 0 .. 64*2560-1
    const int m = idx / (N_DIM / 4);
    const int c = idx - m * (N_DIM / 4);
    f32x4 s = ((const f32x4*)accum)[idx];
    f32x4 ws = ((const f32x4*)wscale)[c];
    f32x4 bs = ((const f32x4*)bias)[c];
    const float xs = xscale[m];
    ((f32x4*)out)[idx] = s * xs * ws + bs;
}

extern "C" void kernel_launch(void* const* d_in, const int* in_sizes, int n_in,
                              void* d_out, int out_size, void* d_ws, size_t ws_size,
                              hipStream_t stream) {
    const float* x = (const float*)d_in[0];
    const int* W = (const int*)d_in[1];
    const float* wscale = (const float*)d_in[2];
    const float* bias = (const float*)d_in[3];
    float* out = (float*)d_out;

    float* xscale = (float*)d_ws;                     // 256 B
    ushort* xq = (ushort*)((char*)d_ws + 4096);       // 1 MB
    float* accum = (float*)((char*)d_ws + 2097152);   // 2.6 MB

    hipMemsetAsync(accum, 0, (size_t)M_DIM * N_DIM * sizeof(float), stream);
    quant_kernel<<<M_DIM, 256, 0, stream>>>(x, xq, xscale);
    gemm_kernel<<<dim3(N_DIM / NTILE, KSPLIT), 256, 0, stream>>>(xq, W, accum);
    finalize_kernel<<<(M_DIM * N_DIM / 4) / 256, 256, 0, stream>>>(
        accum, xscale, wscale, bias, out);
}

// Round 13
// 85.804 us; speedup vs baseline: 1.1250x; 1.1250x over previous
//
#include <hip/hip_runtime.h>

#define M_DIM 64
#define K_DIM 8192
#define N_DIM 10240
#define KSPLIT 8
#define KBLK (K_DIM / KSPLIT)    // 1024 k per block
#define KSTEP 128                 // k per LDS chunk (ints)
#define NGRAN 4                   // granules of 2 chunks each
#define NTILE 64                  // n cols per block (4 waves x 16)
#define BUFB (NTILE * KSTEP * 2)  // bytes per LDS buffer half (16 KB)

typedef __attribute__((ext_vector_type(8))) short short8;
typedef __attribute__((ext_vector_type(4))) float f32x4;
typedef __attribute__((ext_vector_type(4))) int i32x4;

// exact for integer-valued floats |v| <= 127
static __device__ __forceinline__ ushort f2bf_trunc(float f) {
    return (ushort)(__float_as_uint(f) >> 16);
}

// ---------------- Kernel 1: per-token dynamic int8 quantization ----------------
// (verbatim — verified rounds 5/11)
__global__ __launch_bounds__(256) void quant_kernel(
    const float* __restrict__ x,
    ushort* __restrict__ xq,
    float* __restrict__ xscale) {
    const int m = blockIdx.x;
    const int tid = threadIdx.x;
    const float4* xrow = (const float4*)(x + m * K_DIM);
    float4 c[8];
    float mx = 0.f;
#pragma unroll
    for (int i = 0; i < 8; ++i) {
        c[i] = xrow[i * 256 + tid];
        mx = fmaxf(mx, fmaxf(fmaxf(fabsf(c[i].x), fabsf(c[i].y)),
                             fmaxf(fabsf(c[i].z), fabsf(c[i].w))));
    }
#pragma unroll
    for (int off = 32; off; off >>= 1) mx = fmaxf(mx, __shfl_xor(mx, off));
    __shared__ float wmax[4];
    if ((tid & 63) == 0) wmax[tid >> 6] = mx;
    __syncthreads();
    mx = fmaxf(fmaxf(wmax[0], wmax[1]), fmaxf(wmax[2], wmax[3]));
    const float s = mx / 127.0f;
    if (tid == 0) xscale[m] = s;

    ushort4* qrow = (ushort4*)(xq + m * K_DIM);
#pragma unroll
    for (int i = 0; i < 8; ++i) {
        float q0 = fminf(fmaxf(rintf(c[i].x / s), -127.f), 127.f);
        float q1 = fminf(fmaxf(rintf(c[i].y / s), -127.f), 127.f);
        float q2 = fminf(fmaxf(rintf(c[i].z / s), -127.f), 127.f);
        float q3 = fminf(fmaxf(rintf(c[i].w / s), -127.f), 127.f);
        ushort4 o;
        o.x = f2bf_trunc(q0);
        o.y = f2bf_trunc(q1);
        o.z = f2bf_trunc(q2);
        o.w = f2bf_trunc(q3);
        qrow[i * 256 + tid] = o;
    }
}

// ---------------- Kernel 2: granule-paired LDS pipeline ------------------------
// grid (160, 8), 4 waves, 64 KB LDS -> 2 blocks/CU. Fetch granule = 2 chunks:
// W read 1KB-contiguous per instruction (one full 256-int row segment);
// lane<32 holds the even chunk -> LDS buf0, lane>=32 the odd chunk -> buf1
// (pure per-lane addressing, no divergence). Both chunks computed back-to-back
// -> 2 syncs per 256 k (half of round 11). Swizzle law identical to r11.
__global__ __launch_bounds__(256, 2) void gemm_kernel(
    const ushort* __restrict__ xq,   // bf16 bits [64, 8192]
    const int* __restrict__ W,       // int32 [10240, 8192], |v| <= 127
    float* __restrict__ partials) {  // f32 [KSPLIT][64][10240]
    const int tid = threadIdx.x;
    const int w = tid >> 6;
    const int lane = tid & 63;
    const int r16 = lane & 15;
    const int kgrp = lane >> 4;
    const int n0 = blockIdx.x * NTILE;
    const int kb = blockIdx.y;
    const int k0 = kb * KBLK;

    __shared__ __align__(16) ushort Abuf[2][NTILE * KSTEP];  // 2 x 16 KB
    __shared__ __align__(16) ushort Bbuf[2][NTILE * KSTEP];  // 2 x 16 KB

    i32x4 aB[16];   // W granule: 16 instrs x 1KB-contiguous (one row x 256 ints)
    short8 aA[8];   // A granule: 8 instrs x 1KB (2 rows x 256 ushorts)

#define ISSUE_B2(g)                                                            \
    {                                                                          \
        const int* base = W + k0 + (g) * 256 + lane * 4;                       \
        _Pragma("unroll") for (int i = 0; i < 16; ++i) {                       \
            aB[i] = *(const i32x4*)(base + (size_t)(n0 + w * 16 + i) * K_DIM); \
        }                                                                      \
    }
#define ISSUE_A2(g)                                                            \
    {                                                                          \
        const ushort* base = xq + k0 + (g) * 256 + (lane & 31) * 8;            \
        _Pragma("unroll") for (int i = 0; i < 8; ++i) {                        \
            const int row = w * 16 + i * 2 + (lane >> 5);                      \
            aA[i] = *(const short8*)(base + row * K_DIM);                      \
        }                                                                      \
    }
// writes BOTH chunks of the granule: lane half selects destination buffer
#define WRITE_B2()                                                             \
    {                                                                          \
        char* bb = (char*)&Bbuf[0][0] + (lane >> 5) * BUFB;                    \
        _Pragma("unroll") for (int i = 0; i < 16; ++i) {                       \
            const int row = w * 16 + i;                                        \
            ushort4 h;                                                         \
            h.x = f2bf_trunc((float)aB[i][0]);                                 \
            h.y = f2bf_trunc((float)aB[i][1]);                                 \
            h.z = f2bf_trunc((float)aB[i][2]);                                 \
            h.w = f2bf_trunc((float)aB[i][3]);                                 \
            const int off = ((lane & 31) * 8) ^ ((row & 7) << 4);              \
            *(ushort4*)(bb + row * 256 + off) = h;                             \
        }                                                                      \
    }
#define WRITE_A2()                                                             \
    {                                                                          \
        char* ab = (char*)&Abuf[0][0] + ((lane & 31) >> 4) * BUFB;             \
        _Pragma("unroll") for (int i = 0; i < 8; ++i) {                        \
            const int row = w * 16 + i * 2 + (lane >> 5);                      \
            const int off = ((lane & 15) * 16) ^ ((row & 7) << 4);             \
            *(short8*)(ab + row * 256 + off) = aA[i];                          \
        }                                                                      \
    }
#define COMPUTE(bufi)                                                          \
    {                                                                          \
        _Pragma("unroll") for (int ks = 0; ks < 4; ++ks) {                     \
            const int swz = (ks * 64 + kgrp * 16) ^ ((r16 & 7) << 4);          \
            short8 bfrag = *(const short8*)(                                   \
                (char*)&Bbuf[bufi][(w * 16 + r16) * KSTEP] + swz);             \
            _Pragma("unroll") for (int mt = 0; mt < 4; ++mt) {                 \
                short8 afrag = *(const short8*)(                               \
                    (char*)&Abuf[bufi][(mt * 16 + r16) * KSTEP] + swz);        \
                acc[mt] = __builtin_amdgcn_mfma_f32_16x16x32_bf16(             \
                    afrag, bfrag, acc[mt], 0, 0, 0);                           \
            }                                                                  \
        }                                                                      \
    }

    f32x4 acc[4];
#pragma unroll
    for (int i = 0; i < 4; ++i) acc[i] = (f32x4){0.f, 0.f, 0.f, 0.f};

    // granule 0
    ISSUE_B2(0)
    ISSUE_A2(0)
    WRITE_B2()
    WRITE_A2()
    __syncthreads();
    ISSUE_B2(1)
    ISSUE_A2(1)
    COMPUTE(0)
    COMPUTE(1)
    __syncthreads();

    // granule 1
    WRITE_B2()
    WRITE_A2()
    ISSUE_B2(2)
    ISSUE_A2(2)
    __syncthreads();
    COMPUTE(0)
    COMPUTE(1)
    __syncthreads();

    // granule 2
    WRITE_B2()
    WRITE_A2()
    ISSUE_B2(3)
    ISSUE_A2(3)
    __syncthreads();
    COMPUTE(0)
    COMPUTE(1)
    __syncthreads();

    // granule 3
    WRITE_B2()
    WRITE_A2()
    __syncthreads();
    COMPUTE(0)
    COMPUTE(1)

    // epilogue: C via LDS for coalesced partials write (r11 verbatim)
    __syncthreads();
    float* Cl = (float*)&Abuf[0][0];  // [64 m][64 n] f32 = 16 KB
#pragma unroll
    for (int mt = 0; mt < 4; ++mt)
#pragma unroll
        for (int j = 0; j < 4; ++j)
            Cl[(mt * 16 + kgrp * 4 + j) * 64 + w * 16 + r16] = acc[mt][j];
    __syncthreads();
    float* pb = partials + (size_t)kb * (M_DIM * N_DIM);
#pragma unroll
    for (int i = 0; i < 4; ++i) {
        const int idx = tid + 256 * i;
        const int m = idx >> 4;
        const int ch = idx & 15;
        *(f32x4*)(pb + m * N_DIM + n0 + ch * 4) = ((const f32x4*)Cl)[idx];
    }
#undef ISSUE_B2
#undef ISSUE_A2
#undef WRITE_A2
#undef WRITE_B2
#undef COMPUTE
}

// ---------------- Kernel 3: split-K reduce + dequant + bias --------------------
// (verbatim — verified rounds 5/11)
__global__ __launch_bounds__(256) void reduce_kernel(
    const float* __restrict__ partials,
    const float* __restrict__ xscale,
    const float* __restrict__ wscale,
    const float* __restrict__ bias,
    float* __restrict__ out) {
    const int idx = blockIdx.x * 256 + threadIdx.x;  // 0 .. 64*2560-1
    const int m = idx / (N_DIM / 4);
    const int c = idx - m * (N_DIM / 4);
    const f32x4* P = (const f32x4*)partials;
    f32x4 s = (f32x4){0.f, 0.f, 0.f, 0.f};
#pragma unroll
    for (int p = 0; p < KSPLIT; ++p)
        s += P[((size_t)p * M_DIM + m) * (N_DIM / 4) + c];
    f32x4 ws = ((const f32x4*)wscale)[c];
    f32x4 bs = ((const f32x4*)bias)[c];
    const float xs = xscale[m];
    ((f32x4*)out)[idx] = s * xs * ws + bs;
}

extern "C" void kernel_launch(void* const* d_in, const int* in_sizes, int n_in,
                              void* d_out, int out_size, void* d_ws, size_t ws_size,
                              hipStream_t stream) {
    const float* x = (const float*)d_in[0];
    const int* W = (const int*)d_in[1];
    const float* wscale = (const float*)d_in[2];
    const float* bias = (const float*)d_in[3];
    float* out = (float*)d_out;

    float* xscale = (float*)d_ws;                       // 256 B
    ushort* xq = (ushort*)((char*)d_ws + 4096);         // 1 MB
    float* partials = (float*)((char*)d_ws + 2097152);  // 21 MB

    quant_kernel<<<M_DIM, 256, 0, stream>>>(x, xq, xscale);
    gemm_kernel<<<dim3(N_DIM / NTILE, KSPLIT), 256, 0, stream>>>(xq, W, partials);
    reduce_kernel<<<(M_DIM * N_DIM / 4) / 256, 256, 0, stream>>>(
        partials, xscale, wscale, bias, out);
}